// Round 7
// baseline (831.366 us; speedup 1.0000x reference)
//
#include <hip/hip_runtime.h>
#include <cmath>

// ---------------------------------------------------------------------------
// Problem: out = x @ dequant(qweight, meta, scale)
//   x      : fp32 [M,K]; qweight: int32 [K,N] in [0,16)
//   meta   : int32 [K/4,N] in [0,6); scale: fp32 [K/128,N]; out: fp32 [M,N]
// R12: FUSED dequant-into-GEMM. Evidence: pool (wall - gemm) stuck at
// 255-300us across 4 different standalone dequant kernels -> the two-pass
// wt round-trip (serial dequant + 64MB write + 101MB re-read) is structural
// waste, while gemm idles at MfmaUtil 42 / VALUBusy 15. B-staging becomes
// reg-staged dequant (T14 issue@P2 / write@P4) producing the identical
// swizzled LDS image (slot = c ^ (r&7)); A keeps global_load_lds. Single
// vmcnt(0)@P4 with 2-phase slack. wt + chunk loop + dequant kernel deleted.
// Dequant math bit-identical (same f2bf RNE + LUT) -> absmax unchanged.
// ---------------------------------------------------------------------------

typedef __attribute__((ext_vector_type(8))) short bf16x8;
typedef __attribute__((ext_vector_type(4))) float f32x4;
typedef __attribute__((ext_vector_type(4))) unsigned int u32x4;

__device__ inline unsigned short f2bf(float f) {
    union { float f; unsigned u; } v; v.f = f;
    unsigned r = (v.u + 0x7FFFu + ((v.u >> 16) & 1u)) >> 16;  // RNE
    return (unsigned short)r;
}

// ---------------------------------------------------------------------------
// Kernel 0: x fp32 -> bf16, 8 elements/thread, fully coalesced (R1-proven).
// ---------------------------------------------------------------------------
__global__ __launch_bounds__(256) void convert_x(
    const float* __restrict__ x, unsigned short* __restrict__ xb, long long total)
{
    const long long base = ((long long)blockIdx.x * 256 + threadIdx.x) * 8;
    if (base + 8 > total) return;
    const float4 a = *reinterpret_cast<const float4*>(x + base);
    const float4 b = *reinterpret_cast<const float4*>(x + base + 4);
    u32x4 o;
    o.x = (unsigned)f2bf(a.x) | ((unsigned)f2bf(a.y) << 16);
    o.y = (unsigned)f2bf(a.z) | ((unsigned)f2bf(a.w) << 16);
    o.z = (unsigned)f2bf(b.x) | ((unsigned)f2bf(b.y) << 16);
    o.w = (unsigned)f2bf(b.z) | ((unsigned)f2bf(b.w) << 16);
    *reinterpret_cast<u32x4*>(xb + base) = o;
}

// ---------------------------------------------------------------------------
// Kernel 1: fused 256x256 8-phase GEMM with inline B dequant.
// 8 waves 2Mx4N, BK=64, 128KiB LDS, chunk-XOR swizzle, L2-rect grid map.
// B-staging (replaces DMA): thread owns row r = 32*w + (lane&31) (n dir),
// chunks c = 4*(lane>>5)+g, g=0..3 (8 k each). Per K-tile: 32 q + 8 meta +
// 1 scale dword loads (coalesced 2x128B per instr), dequant in regs,
// 4x ds_write_b128 at slot = c ^ (r&7)  [2 lanes/slot per 16-lane phase =
// conflict-free; identical layout to the proven DMA image].
// Schedule per K-tile T (tile in buf, A(T+1)->obuf DMA, B(T+2)->buf regs):
//   P1: 8 a-rds(qm0); STAGE_A h0;             MFMA q(0,0) bcur
//   P2: 4 b1-rds;     STAGE_A h1; B-loads;    MFMA q(0,1) bnxt
//   P3: 8 a-rds(qm1);                         MFMA q(1,1) bnxt
//   P4: MFMA q(1,0) bcur; vmcnt(0) [2-phase slack]; dequant+4 ds_write;
//       4 b0next-rds(obuf); lgkm(0); BAR.
// ---------------------------------------------------------------------------
#define BAR() do { asm volatile("" ::: "memory"); \
                   __builtin_amdgcn_s_barrier(); \
                   asm volatile("" ::: "memory"); } while (0)

#define GLDS(g, s) __builtin_amdgcn_global_load_lds( \
    (const __attribute__((address_space(1))) void*)(g), \
    (__attribute__((address_space(3))) void*)(s), 16, 0, 0)

#define MFMA(d, x, y) d = __builtin_amdgcn_mfma_f32_16x16x32_bf16(x, y, d, 0, 0, 0)

__global__ __launch_bounds__(512, 2) void gemm256(
    const unsigned short* __restrict__ A,   // bf16 [M,K] (converted x)
    const int* __restrict__ Q,              // int32 [K,N]
    const int* __restrict__ Meta,           // int32 [K/4,N]
    const float* __restrict__ Scale,        // fp32 [K/128,N]
    float* __restrict__ C,                  // fp32 [M,N]
    int M, int N, int K)
{
    __shared__ __align__(16) unsigned short As[32768];
    __shared__ __align__(16) unsigned short Bs[32768];

    const int t    = threadIdx.x;
    const int w    = t >> 6;
    const int lane = t & 63;
    const int wm   = w >> 2;
    const int wn   = w & 3;
    const int l16  = lane & 15;
    const int quad = lane >> 4;

    // --- L2-rectangle grid mapping (R7-verified) ---------------------------
    const int gx = gridDim.x, gy = gridDim.y;
    int bid = blockIdx.y * gx + blockIdx.x;
    const int nwg = gx * gy;
    int m0, n0;
    if ((nwg & 7) == 0 && (gy & 1) == 0 && (gx & 3) == 0) {
        const int xcd = bid & 7;
        const int idx = bid >> 3;
        const int cpr = gx >> 2;
        const int lr  = idx / cpr;
        const int lc  = idx - lr * cpr;
        m0 = ((xcd >> 2) * (gy >> 1) + lr) * 256;
        n0 = ((xcd & 3) * cpr + lc) * 256;
    } else {
        int b2 = bid;
        if (nwg >= 8) {
            const int q8 = nwg >> 3, r8 = nwg & 7;
            const int xcd = bid & 7, off = bid >> 3;
            b2 = (xcd < r8 ? xcd * (q8 + 1) : r8 * (q8 + 1) + (xcd - r8) * q8) + off;
        }
        n0 = (b2 % gx) * 256;
        m0 = (b2 / gx) * 256;
    }

    // --- A staging (DMA, pre-swizzled source; unchanged) -------------------
    const int    csrc = ((lane & 7) ^ ((lane >> 3) & 7)) * 8;
    const size_t aB = (size_t)(m0 + w * 8 + (lane >> 3)) * K + csrc;
    const size_t J  = (size_t)64 * K;
    const size_t H  = (size_t)128 * K;
    const int sdst  = w * 512;

    // --- B fused staging thread map ----------------------------------------
    const int brow = w * 32 + (lane & 31);       // B row (n) 0..255
    const int cb   = (lane >> 5) * 4;            // chunk base 0 or 4
    const int bn   = n0 + brow;                  // global n column
    const int* __restrict__ qcol = Q + bn;
    const int* __restrict__ mcol = Meta + bn;
    const float* __restrict__ scol = Scale + bn;
    const int bwr  = (brow >> 7) * 8192 + (brow & 127) * 64;  // ushort idx
    const int r7   = brow & 7;
    const unsigned lut = 0xCA6953u;

    // --- fragment ds_read bases (unchanged) --------------------------------
    const int sw0 = ((quad ^ (lane & 7)) * 8);
    const int sw1 = (((4 + quad) ^ (lane & 7)) * 8);
    const int aR  = wm * 8192 + l16 * 64;
    const int bR  = (wn >> 1) * 8192 + ((wn & 1) * 64 + l16) * 64;

    int kA = 0, kB = 0;

#define STAGE_A(buf, h) do { \
    GLDS(A + aB + (size_t)(h) * H + kA, &As[(buf)*16384 + (h)*8192 + sdst]); \
    GLDS(A + aB + (size_t)(h) * H + J + kA, &As[(buf)*16384 + (h)*8192 + 4096 + sdst]); \
  } while (0)

    int   qreg[4][8];
    int   mreg[4][2];
    float screg;

#define BSTAGE_LOAD() do { \
    screg = scol[(size_t)(kB >> 7) * N]; \
    _Pragma("unroll") for (int g = 0; g < 4; ++g) { \
      const int kk = kB + (cb + g) * 8; \
      mreg[g][0] = mcol[(size_t)((kk >> 2) + 0) * N]; \
      mreg[g][1] = mcol[(size_t)((kk >> 2) + 1) * N]; \
      _Pragma("unroll") for (int j = 0; j < 8; ++j) \
        qreg[g][j] = qcol[(size_t)(kk + j) * N]; \
    } \
  } while (0)

#define BSTAGE_WRITE(buf) do { \
    _Pragma("unroll") for (int g = 0; g < 4; ++g) { \
      const int slot = (cb + g) ^ r7; \
      u32x4 pk; \
      _Pragma("unroll") for (int pp = 0; pp < 4; ++pp) { \
        unsigned short wv0, wv1; \
        { const int j = pp * 2; \
          const int mv = mreg[g][j >> 2]; \
          const float wf = ((lut >> (mv * 4 + (j & 3))) & 1u) \
              ? (float)(qreg[g][j] - 8) * screg : 0.0f; \
          wv0 = f2bf(wf); } \
        { const int j = pp * 2 + 1; \
          const int mv = mreg[g][j >> 2]; \
          const float wf = ((lut >> (mv * 4 + (j & 3))) & 1u) \
              ? (float)(qreg[g][j] - 8) * screg : 0.0f; \
          wv1 = f2bf(wf); } \
        pk[pp] = (unsigned)wv0 | ((unsigned)wv1 << 16); \
      } \
      *reinterpret_cast<u32x4*>(&Bs[(buf) * 16384 + bwr + slot * 8]) = pk; \
    } \
  } while (0)

    f32x4 acc[8][4];
    #pragma unroll
    for (int i = 0; i < 8; ++i)
        #pragma unroll
        for (int j = 0; j < 4; ++j)
            acc[i][j] = (f32x4){0.f, 0.f, 0.f, 0.f};

    // prologue: B(T0)->buf0 (regs), A(T0)->buf0 (DMA), B(T1)->buf1 (regs)
    BSTAGE_LOAD();                       // B(T0), kB=0
    STAGE_A(0, 0); STAGE_A(0, 1); kA += 64;
    asm volatile("s_waitcnt vmcnt(4)" ::: "memory");   // B(T0) loads done
    BSTAGE_WRITE(0);
    kB += 64;
    BSTAGE_LOAD();                       // B(T1), kB=64
    asm volatile("s_waitcnt vmcnt(0)" ::: "memory");   // all done (prologue)
    BSTAGE_WRITE(1);
    kB += 64;                            // next to stage = T2 (k=128)
    asm volatile("s_waitcnt lgkmcnt(0)" ::: "memory");
    BAR();

    bf16x8 a[4][2], bA_[2][2], bB_[2][2];

    // preload b0 of tile 0 from buf0
    #pragma unroll
    for (int j = 0; j < 2; ++j) {
        bA_[j][0] = *(const bf16x8*)&Bs[bR + j * 1024 + sw0];
        bA_[j][1] = *(const bf16x8*)&Bs[bR + j * 1024 + sw1];
    }

#define PHASES(buf, obuf, bcur, bnxt) do { \
  /* P1: 8 a-rds (qm0), STAGE_A(T+1)h0 -> obuf, mfma q(0,0) w/ bcur */ \
  _Pragma("unroll") for (int i = 0; i < 4; ++i) { \
    a[i][0] = *(const bf16x8*)&As[(buf)*16384 + aR + i*1024 + sw0]; \
    a[i][1] = *(const bf16x8*)&As[(buf)*16384 + aR + i*1024 + sw1]; } \
  STAGE_A(obuf, 0); \
  BAR(); \
  asm volatile("s_waitcnt lgkmcnt(0)" ::: "memory"); \
  __builtin_amdgcn_s_setprio(1); \
  _Pragma("unroll") for (int i = 0; i < 4; ++i) \
    _Pragma("unroll") for (int j = 0; j < 2; ++j) { \
      MFMA(acc[i][j], a[i][0], bcur[j][0]); MFMA(acc[i][j], a[i][1], bcur[j][1]); } \
  __builtin_amdgcn_s_setprio(0); \
  BAR(); \
  /* P2: 4 b1-rds -> bnxt, STAGE_A h1, issue B(T+2) loads, mfma q(0,1) */ \
  _Pragma("unroll") for (int j = 0; j < 2; ++j) { \
    bnxt[j][0] = *(const bf16x8*)&Bs[(buf)*16384 + bR + (2+j)*1024 + sw0]; \
    bnxt[j][1] = *(const bf16x8*)&Bs[(buf)*16384 + bR + (2+j)*1024 + sw1]; } \
  STAGE_A(obuf, 1); kA += 64; if (kA >= K) kA = 0; \
  BSTAGE_LOAD(); kB += 64; if (kB >= K) kB = 0; \
  BAR(); \
  asm volatile("s_waitcnt lgkmcnt(0)" ::: "memory"); \
  __builtin_amdgcn_s_setprio(1); \
  _Pragma("unroll") for (int i = 0; i < 4; ++i) \
    _Pragma("unroll") for (int j = 0; j < 2; ++j) { \
      MFMA(acc[i][2+j], a[i][0], bnxt[j][0]); MFMA(acc[i][2+j], a[i][1], bnxt[j][1]); } \
  __builtin_amdgcn_s_setprio(0); \
  BAR(); \
  /* P3: 8 a-rds (qm1), mfma q(1,1) */ \
  _Pragma("unroll") for (int i = 0; i < 4; ++i) { \
    a[i][0] = *(const bf16x8*)&As[(buf)*16384 + aR + (4+i)*1024 + sw0]; \
    a[i][1] = *(const bf16x8*)&As[(buf)*16384 + aR + (4+i)*1024 + sw1]; } \
  BAR(); \
  asm volatile("s_waitcnt lgkmcnt(0)" ::: "memory"); \
  __builtin_amdgcn_s_setprio(1); \
  _Pragma("unroll") for (int i = 0; i < 4; ++i) \
    _Pragma("unroll") for (int j = 0; j < 2; ++j) { \
      MFMA(acc[4+i][2+j], a[i][0], bnxt[j][0]); MFMA(acc[4+i][2+j], a[i][1], bnxt[j][1]); } \
  __builtin_amdgcn_s_setprio(0); \
  BAR(); \
  /* P4: mfma q(1,0) (regs only), then vmcnt(0) [B loads, 2-phase slack], */ \
  /* dequant + 4 ds_write (buf B, identical swizzled image), b0next-rds,  */ \
  /* lgkm(0), BAR. */ \
  __builtin_amdgcn_s_setprio(1); \
  _Pragma("unroll") for (int i = 0; i < 4; ++i) \
    _Pragma("unroll") for (int j = 0; j < 2; ++j) { \
      MFMA(acc[4+i][j], a[i][0], bcur[j][0]); MFMA(acc[4+i][j], a[i][1], bcur[j][1]); } \
  __builtin_amdgcn_s_setprio(0); \
  asm volatile("s_waitcnt vmcnt(0)" ::: "memory"); \
  BSTAGE_WRITE(buf); \
  _Pragma("unroll") for (int j = 0; j < 2; ++j) { \
    bnxt[j][0] = *(const bf16x8*)&Bs[(obuf)*16384 + bR + j*1024 + sw0]; \
    bnxt[j][1] = *(const bf16x8*)&Bs[(obuf)*16384 + bR + j*1024 + sw1]; } \
  asm volatile("s_waitcnt lgkmcnt(0)" ::: "memory"); \
  BAR(); \
} while (0)

    const int NIT = K >> 7;   // 2 K-tiles (128 k) per iteration
    for (int it = 0; it < NIT; ++it) {
        PHASES(0, 1, bA_, bB_);
        PHASES(1, 0, bB_, bA_);
    }

    asm volatile("s_waitcnt vmcnt(0)" ::: "memory");  // drain tail A DMA

    // epilogue: C/D layout col = lane&15, row = quad*4 + reg (m89-verified)
    const int mBase = m0 + wm * 128;
    const int nBase = n0 + wn * 64;
    #pragma unroll
    for (int i = 0; i < 8; ++i) {
        const int mrow = mBase + i * 16 + quad * 4;
        #pragma unroll
        for (int j = 0; j < 4; ++j) {
            const int ncol = nBase + j * 16 + l16;
            #pragma unroll
            for (int r = 0; r < 4; ++r)
                C[(size_t)(mrow + r) * N + ncol] = acc[i][j][r];
        }
    }
#undef STAGE_A
#undef BSTAGE_LOAD
#undef BSTAGE_WRITE
#undef PHASES
}

extern "C" void kernel_launch(void* const* d_in, const int* in_sizes, int n_in,
                              void* d_out, int out_size, void* d_ws, size_t ws_size,
                              hipStream_t stream)
{
    const float* x     = (const float*)d_in[0];   // fp32 [M,K]
    const int*   q     = (const int*)d_in[1];     // [K,N]
    const int*   meta  = (const int*)d_in[2];     // [K/4,N]
    const float* scale = (const float*)d_in[3];   // fp32 [K/128,N]
    float*       out   = (float*)d_out;           // fp32 [M,N]

    const double s0 = (double)in_sizes[0];
    const double s1 = (double)in_sizes[1];
    const int K = (int)llround(sqrt(s0 * s1 / (double)out_size));
    const int M = in_sizes[0] / K;
    const int N = in_sizes[1] / K;

    // ws: only x_bf16 now (M*K*2 bytes)
    unsigned short* xb = (unsigned short*)d_ws;
    const long long total = (long long)M * K;

    convert_x<<<dim3((unsigned)((total / 8 + 255) / 256)), dim3(256), 0, stream>>>(
        x, xb, total);

    dim3 g2(N / 256, M / 256);
    gemm256<<<g2, dim3(512), 0, stream>>>(xb, q, meta, scale, out, M, N, K);
}